// Round 3
// baseline (832.573 us; speedup 1.0000x reference)
//
#include <hip/hip_runtime.h>
#include <hip/hip_bf16.h>
#include <math.h>

typedef __bf16 bf16_t;
typedef bf16_t bf16x8 __attribute__((ext_vector_type(8)));
typedef bf16_t bf16x4 __attribute__((ext_vector_type(4)));
typedef float  f32x4  __attribute__((ext_vector_type(4)));

// ---------------------------------------------------------------------------
// fp32 -> bf16 conversion, float4 loads, 8B stores
// ---------------------------------------------------------------------------
__global__ __launch_bounds__(256) void cvt_f32_bf16(
    const float* __restrict__ in, bf16_t* __restrict__ out, int n4) {
  int i = blockIdx.x * 256 + threadIdx.x;
  if (i >= n4) return;
  float4 v = ((const float4*)in)[i];
  bf16x4 o;
  o[0] = (bf16_t)v.x; o[1] = (bf16_t)v.y; o[2] = (bf16_t)v.z; o[3] = (bf16_t)v.w;
  ((bf16x4*)out)[i] = o;
}

// ---------------------------------------------------------------------------
// bf16 LDS-tiled transpose: in [R,C] -> out [C,R], per-batch via blockIdx.z
// ---------------------------------------------------------------------------
__global__ __launch_bounds__(256) void transpose_bf16(
    const bf16_t* __restrict__ in, bf16_t* __restrict__ out, int R, int C) {
  __shared__ bf16_t t[64][65];
  size_t boff = (size_t)blockIdx.z * R * C;
  in += boff; out += boff;
  int r0 = blockIdx.y * 64, c0 = blockIdx.x * 64;
  int x = threadIdx.x & 63, y4 = threadIdx.x >> 6;
  #pragma unroll
  for (int yy = y4; yy < 64; yy += 4)
    t[yy][x] = in[(size_t)(r0 + yy) * C + c0 + x];
  __syncthreads();
  #pragma unroll
  for (int yy = y4; yy < 64; yy += 4)
    out[(size_t)(c0 + yy) * R + r0 + x] = t[x][yy];
}

// ---------------------------------------------------------------------------
// Row softmax over fp32 logits [nrows x 2048]; writes normalized bf16 P
// in-place into the low 4KB of each 8KB row (element stride stays 4096 bf16).
// One block (256 thr) per row; 8 floats/thread. All global reads complete
// before the reduction barriers, so the in-place write is race-free.
// ---------------------------------------------------------------------------
__global__ __launch_bounds__(256) void softmax_rows(float* __restrict__ sc) {
  float* rp = sc + (size_t)blockIdx.x * 2048;
  int tid = threadIdx.x;
  const float4* rp4 = (const float4*)rp;
  float4 v0 = rp4[tid * 2 + 0];
  float4 v1 = rp4[tid * 2 + 1];
  float f[8] = {v0.x, v0.y, v0.z, v0.w, v1.x, v1.y, v1.z, v1.w};

  float m = f[0];
  #pragma unroll
  for (int t = 1; t < 8; t++) m = fmaxf(m, f[t]);
  #pragma unroll
  for (int o = 32; o; o >>= 1) m = fmaxf(m, __shfl_xor(m, o));
  __shared__ float redm[4];
  if ((tid & 63) == 0) redm[tid >> 6] = m;
  __syncthreads();
  m = fmaxf(fmaxf(redm[0], redm[1]), fmaxf(redm[2], redm[3]));

  float s = 0.f;
  #pragma unroll
  for (int t = 0; t < 8; t++) { f[t] = __expf(f[t] - m); s += f[t]; }
  #pragma unroll
  for (int o = 32; o; o >>= 1) s += __shfl_xor(s, o);
  __shared__ float reds[4];
  if ((tid & 63) == 0) reds[tid >> 6] = s;
  __syncthreads();
  s = reds[0] + reds[1] + reds[2] + reds[3];
  float inv = 1.0f / s;

  bf16x8 o8;
  #pragma unroll
  for (int t = 0; t < 8; t++) o8[t] = (bf16_t)(f[t] * inv);
  ((bf16x8*)rp)[tid] = o8;
}

// ---------------------------------------------------------------------------
// bf16 MFMA GEMM, C = scale * (A @ B^T) + bias
//   A [M,K] row-major (lda elements), B [N,K] row-major (ldb elements)
//   C [M,N] (ldc elements), CT = float or bf16_t. Batched via blockIdx.z.
// Grid: (M/128, N/128, batch).  blockIdx.x = M-tile so the blocks sharing an
// A-panel (same x, ids x + gridX*y, gridX % 8 == 0) land on ONE XCD -> the
// panel is served from that XCD's L2 instead of re-fetched 8x from HBM.
// Epilogue repacks C through LDS for coalesced full-line vector stores.
// Requires M%128==0, N%128==0, K%64==0, lda/ldb 8-elem, ldc 4-elem aligned.
// ---------------------------------------------------------------------------
#define TM 128
#define TN 128
#define TK 64

__device__ __forceinline__ void load16_lds(const bf16_t* g, bf16_t* l) {
  __builtin_amdgcn_global_load_lds(
      (__attribute__((address_space(1))) void*)const_cast<bf16_t*>(g),
      (__attribute__((address_space(3))) void*)l, 16, 0, 0);
}

template <typename CT>
__global__ __launch_bounds__(256, 2) void gemm_bt(
    const bf16_t* __restrict__ A, int lda, size_t strA,
    const bf16_t* __restrict__ B, int ldb, size_t strB,
    CT* __restrict__ C, int ldc, size_t strC,
    const float* __restrict__ bias, float scale,
    int M, int N, int K) {
  __shared__ __align__(16) char smem[(TM * TK + TN * TK) * 2];  // 32 KB
  bf16_t* As = (bf16_t*)smem;
  bf16_t* Bs = As + TM * TK;

  A += (size_t)blockIdx.z * strA;
  B += (size_t)blockIdx.z * strB;
  C += (size_t)blockIdx.z * strC;
  int m0 = blockIdx.x * TM;   // M-tile on x (XCD swizzle)
  int n0 = blockIdx.y * TN;
  int tid  = threadIdx.x;
  int lane = tid & 63;
  int wv   = tid >> 6;        // wave id 0..3
  int wrow = wv >> 1;         // 2x2 waves of 64x64
  int wcol = wv & 1;

  f32x4 acc[4][4];
  #pragma unroll
  for (int i = 0; i < 4; i++)
    #pragma unroll
    for (int j = 0; j < 4; j++) acc[i][j] = (f32x4)0.f;

  int lrow = lane & 15;
  int lk   = (lane >> 4) * 8;

  for (int k0 = 0; k0 < K; k0 += TK) {
    // stage 128x64 bf16 tiles of A and B: 4 wave-issues each, 16B/lane.
    #pragma unroll
    for (int i = 0; i < 4; i++) {
      int chunk  = i * 4096 + wv * 1024;   // wave-uniform byte offset in tile
      int lchunk = chunk + lane * 16;      // this lane's byte offset
      int row = lchunk >> 7;               // 128 B per row (TK*2)
      int kb  = (lchunk & 127) >> 1;       // element offset within row
      load16_lds(A + (size_t)(m0 + row) * lda + k0 + kb, As + (chunk >> 1));
      load16_lds(B + (size_t)(n0 + row) * ldb + k0 + kb, Bs + (chunk >> 1));
    }
    __syncthreads();   // drains vmcnt for global_load_lds

    #pragma unroll
    for (int ks = 0; ks < TK; ks += 32) {
      bf16x8 af[4], bfr[4];
      #pragma unroll
      for (int i = 0; i < 4; i++)
        af[i] = *(const bf16x8*)&As[(wrow * 64 + i * 16 + lrow) * TK + ks + lk];
      #pragma unroll
      for (int j = 0; j < 4; j++)
        bfr[j] = *(const bf16x8*)&Bs[(wcol * 64 + j * 16 + lrow) * TK + ks + lk];
      #pragma unroll
      for (int i = 0; i < 4; i++)
        #pragma unroll
        for (int j = 0; j < 4; j++)
          acc[i][j] = __builtin_amdgcn_mfma_f32_16x16x32_bf16(af[i], bfr[j],
                                                              acc[i][j], 0, 0, 0);
    }
    __syncthreads();
  }

  // ---- epilogue: repack C through LDS (two 64x128 fp32 halves = 32 KB) ----
  // acc mapping: col = lane&15 (+j*16, +wcol*64), row = (lane>>4)*4+r (+i*16,
  // +wrow*64)  [m89-verified]
  float* Cs = (float*)smem;
  #pragma unroll
  for (int h = 0; h < 2; h++) {
    __syncthreads();           // prior LDS use (K-loop or previous half) done
    if (wrow == h) {           // wave-uniform branch
      #pragma unroll
      for (int i = 0; i < 4; i++) {
        int lr = i * 16 + (lane >> 4) * 4;            // row within 64-row half
        #pragma unroll
        for (int j = 0; j < 4; j++) {
          int lc = wcol * 64 + j * 16 + (lane & 15);  // col within 128
          #pragma unroll
          for (int r = 0; r < 4; r++)
            Cs[(lr + r) * 128 + lc] = acc[i][j][r];
        }
      }
    }
    __syncthreads();
    // linear readback: 8192 floats, 256 threads -> 8 float4 per thread
    #pragma unroll
    for (int io = 0; io < 8; io++) {
      int idx = io * 256 + tid;        // 0..2047 float4 groups
      int r   = idx >> 5;              // row 0..63
      int c4  = (idx & 31) * 4;        // col 0..124
      float4 v = *(const float4*)&Cs[r * 128 + c4];
      int grow = m0 + h * 64 + r;
      int gcol = n0 + c4;
      float4 bv = bias ? *(const float4*)&bias[gcol] : make_float4(0, 0, 0, 0);
      v.x = v.x * scale + bv.x; v.y = v.y * scale + bv.y;
      v.z = v.z * scale + bv.z; v.w = v.w * scale + bv.w;
      CT* cp = C + (size_t)grow * ldc + gcol;
      if constexpr (sizeof(CT) == 4) {
        *(float4*)cp = v;
      } else {
        bf16x4 o;
        o[0] = (bf16_t)v.x; o[1] = (bf16_t)v.y;
        o[2] = (bf16_t)v.z; o[3] = (bf16_t)v.w;
        *(bf16x4*)cp = o;
      }
    }
  }
}

// ---------------------------------------------------------------------------
// Host-side launcher.  Peak workspace: 168 MiB.
//   [W bf16 8MiB][IN 32MiB (bf16 input copy; later SC fp32 2-batch logits)]
//   [Qb 32][Kb 32][VT 32][Xb 32 (V bf16 pre-transpose, then attention X)]
// ---------------------------------------------------------------------------
extern "C" void kernel_launch(void* const* d_in, const int* in_sizes, int n_in,
                              void* d_out, int out_size, void* d_ws, size_t ws_size,
                              hipStream_t stream) {
  const float* query = (const float*)d_in[0];
  const float* key_  = (const float*)d_in[1];
  const float* value = (const float*)d_in[2];
  const float* Wq = (const float*)d_in[3];
  const float* bq = (const float*)d_in[4];
  const float* Wk = (const float*)d_in[5];
  const float* bk = (const float*)d_in[6];
  const float* Wv = (const float*)d_in[7];
  const float* bv = (const float*)d_in[8];
  const float* Wo = (const float*)d_in[9];
  const float* bo = (const float*)d_in[10];
  float* out = (float*)d_out;

  const int Bb = 8, S = 2048, D = 1024;
  const int MS = Bb * S;                    // 16384
  const size_t ND = (size_t)MS * D;         // 16,777,216 elements (32 MiB bf16)
  const size_t WD = (size_t)D * D;          // 1,048,576 elements (2 MiB bf16)
  const int CH = 2;                         // batches per attention chunk

  char* ws = (char*)d_ws;
  bf16_t* Wqb = (bf16_t*)ws;                //  8 MiB of weights
  bf16_t* Wkb = Wqb + WD;
  bf16_t* Wvb = Wkb + WD;
  bf16_t* Wob = Wvb + WD;
  bf16_t* IN  = Wob + WD;                   // 32 MiB: bf16 input copies
  float*  SC  = (float*)IN;                 //   ...later: 2-batch fp32 logits
  bf16_t* Qb  = IN + ND;                    // 32 MiB
  bf16_t* Kb  = Qb + ND;                    // 32 MiB
  bf16_t* VT  = Kb + ND;                    // 32 MiB
  bf16_t* Xb  = VT + ND;                    // 32 MiB: V bf16, then X
  // total: 168 MiB

  const int n4i = (int)(ND / 4), n4w = (int)(WD / 4);

  // weights
  cvt_f32_bf16<<<dim3(n4w / 256), 256, 0, stream>>>(Wq, Wqb, n4w);
  cvt_f32_bf16<<<dim3(n4w / 256), 256, 0, stream>>>(Wk, Wkb, n4w);
  cvt_f32_bf16<<<dim3(n4w / 256), 256, 0, stream>>>(Wv, Wvb, n4w);
  cvt_f32_bf16<<<dim3(n4w / 256), 256, 0, stream>>>(Wo, Wob, n4w);

  // projections, one input at a time through IN (M=16384, N=K=1024)
  dim3 pgrid(MS / TM, D / TN, 1);           // x = M-tiles (XCD swizzle)
  cvt_f32_bf16<<<dim3(n4i / 256), 256, 0, stream>>>(query, IN, n4i);
  gemm_bt<bf16_t><<<pgrid, 256, 0, stream>>>(
      IN, D, 0, Wqb, D, 0, Qb, D, 0, bq, 1.f, MS, D, D);
  cvt_f32_bf16<<<dim3(n4i / 256), 256, 0, stream>>>(key_, IN, n4i);
  gemm_bt<bf16_t><<<pgrid, 256, 0, stream>>>(
      IN, D, 0, Wkb, D, 0, Kb, D, 0, bk, 1.f, MS, D, D);
  cvt_f32_bf16<<<dim3(n4i / 256), 256, 0, stream>>>(value, IN, n4i);
  gemm_bt<bf16_t><<<pgrid, 256, 0, stream>>>(
      IN, D, 0, Wvb, D, 0, Xb, D, 0, bv, 1.f, MS, D, D);  // V into Xb (temp)

  // V^T per batch: [2048,1024] -> [1024,2048]
  transpose_bf16<<<dim3(D / 64, S / 64, Bb), 256, 0, stream>>>(Xb, VT, S, D);

  // attention in 2-batch chunks; SC overlays the now-dead IN region
  for (int c = 0; c < Bb / CH; c++) {
    const bf16_t* Qc = Qb + (size_t)c * CH * S * D;
    const bf16_t* Kc = Kb + (size_t)c * CH * S * D;
    const bf16_t* Vc = VT + (size_t)c * CH * D * S;
    bf16_t*       Xc = Xb + (size_t)c * CH * S * D;

    // scores = Q @ K^T / sqrt(128) -> fp32 (M=N=2048, K=1024)
    gemm_bt<float><<<dim3(S / TM, S / TN, CH), 256, 0, stream>>>(
        Qc, D, (size_t)S * D, Kc, D, (size_t)S * D, SC, S, (size_t)S * S,
        nullptr, 0.08838834764831845f, S, S, D);

    // softmax -> bf16 P in place (row pitch 4096 bf16)
    softmax_rows<<<dim3(CH * S), 256, 0, stream>>>(SC);

    // X = P @ (V^T)^T  (M=2048, N=1024, K=2048)
    gemm_bt<bf16_t><<<dim3(S / TM, D / TN, CH), 256, 0, stream>>>(
        (const bf16_t*)SC, 2 * S, (size_t)S * 2 * S, Vc, S, (size_t)D * S,
        Xc, D, (size_t)S * D, nullptr, 1.f, S, D, S);
  }

  // out = X @ Wo^T + bo -> fp32 (M=16384, N=K=1024)
  gemm_bt<float><<<pgrid, 256, 0, stream>>>(
      Xb, D, 0, Wob, D, 0, out, D, 0, bo, 1.f, MS, D, D);
}

// Round 4
// 679.079 us; speedup vs baseline: 1.2260x; 1.2260x over previous
//
#include <hip/hip_runtime.h>
#include <hip/hip_bf16.h>
#include <math.h>

typedef __bf16 bf16_t;
typedef _Float16 f16_t;
typedef bf16_t bf16x8 __attribute__((ext_vector_type(8)));
typedef bf16_t bf16x4 __attribute__((ext_vector_type(4)));
typedef f16_t  f16x8  __attribute__((ext_vector_type(8)));
typedef f16_t  f16x4  __attribute__((ext_vector_type(4)));
typedef float  f32x4  __attribute__((ext_vector_type(4)));

// ---------------------------------------------------------------------------
// fp32 -> bf16 conversion, float4 loads, 8B stores
// ---------------------------------------------------------------------------
__global__ __launch_bounds__(256) void cvt_f32_bf16(
    const float* __restrict__ in, bf16_t* __restrict__ out, int n4) {
  int i = blockIdx.x * 256 + threadIdx.x;
  if (i >= n4) return;
  float4 v = ((const float4*)in)[i];
  bf16x4 o;
  o[0] = (bf16_t)v.x; o[1] = (bf16_t)v.y; o[2] = (bf16_t)v.z; o[3] = (bf16_t)v.w;
  ((bf16x4*)out)[i] = o;
}

// ---------------------------------------------------------------------------
// bf16 LDS-tiled transpose: in [R,C] -> out [C,R], per-batch via blockIdx.z
// ---------------------------------------------------------------------------
__global__ __launch_bounds__(256) void transpose_bf16(
    const bf16_t* __restrict__ in, bf16_t* __restrict__ out, int R, int C) {
  __shared__ bf16_t t[64][65];
  size_t boff = (size_t)blockIdx.z * R * C;
  in += boff; out += boff;
  int r0 = blockIdx.y * 64, c0 = blockIdx.x * 64;
  int x = threadIdx.x & 63, y4 = threadIdx.x >> 6;
  #pragma unroll
  for (int yy = y4; yy < 64; yy += 4)
    t[yy][x] = in[(size_t)(r0 + yy) * C + c0 + x];
  __syncthreads();
  #pragma unroll
  for (int yy = y4; yy < 64; yy += 4)
    out[(size_t)(c0 + yy) * R + r0 + x] = t[x][yy];
}

// ---------------------------------------------------------------------------
// Row softmax over fp16 logits [nrows x 2048]; overwrites each row in place
// with normalized bf16 P (same 2-byte element pitch, same row addresses).
// One block (256 thr) per row; 8 elems/thread; all reads complete before the
// reduction barriers so the in-place overwrite is race-free.
// ---------------------------------------------------------------------------
__global__ __launch_bounds__(256) void softmax_rows_f16(f16_t* __restrict__ sc) {
  f16_t* rp = sc + (size_t)blockIdx.x * 2048;
  int tid = threadIdx.x;
  f16x8 v = ((const f16x8*)rp)[tid];
  float f[8];
  #pragma unroll
  for (int t = 0; t < 8; t++) f[t] = (float)v[t];

  float m = f[0];
  #pragma unroll
  for (int t = 1; t < 8; t++) m = fmaxf(m, f[t]);
  #pragma unroll
  for (int o = 32; o; o >>= 1) m = fmaxf(m, __shfl_xor(m, o));
  __shared__ float redm[4];
  if ((tid & 63) == 0) redm[tid >> 6] = m;
  __syncthreads();
  m = fmaxf(fmaxf(redm[0], redm[1]), fmaxf(redm[2], redm[3]));

  float s = 0.f;
  #pragma unroll
  for (int t = 0; t < 8; t++) { f[t] = __expf(f[t] - m); s += f[t]; }
  #pragma unroll
  for (int o = 32; o; o >>= 1) s += __shfl_xor(s, o);
  __shared__ float reds[4];
  if ((tid & 63) == 0) reds[tid >> 6] = s;
  __syncthreads();
  s = reds[0] + reds[1] + reds[2] + reds[3];
  float inv = 1.0f / s;

  bf16x8 o8;
  #pragma unroll
  for (int t = 0; t < 8; t++) o8[t] = (bf16_t)(f[t] * inv);
  ((bf16x8*)rp)[tid] = o8;
}

// ---------------------------------------------------------------------------
// epilogue store helpers (full-line coalesced vector stores)
// ---------------------------------------------------------------------------
__device__ __forceinline__ void store4(float* p, float4 v) { *(float4*)p = v; }
__device__ __forceinline__ void store4(bf16_t* p, float4 v) {
  bf16x4 o; o[0] = (bf16_t)v.x; o[1] = (bf16_t)v.y;
  o[2] = (bf16_t)v.z; o[3] = (bf16_t)v.w; *(bf16x4*)p = o;
}
__device__ __forceinline__ void store4(f16_t* p, float4 v) {
  f16x4 o; o[0] = (f16_t)v.x; o[1] = (f16_t)v.y;
  o[2] = (f16_t)v.z; o[3] = (f16_t)v.w; *(f16x4*)p = o;
}

// ---------------------------------------------------------------------------
// bf16 MFMA GEMM, C = scale * (A @ B^T) + bias
//   A [M,K] row-major (lda elements), B [N,K] row-major (ldb elements)
//   C [M,N] (ldc elements), CT in {float, bf16_t, f16_t}. Batch via blockIdx.z.
// Grid: (M/128, N/128, batch); blockIdx.x = M-tile (XCD swizzle: same-A blocks
// land on one XCD so the A-panel is L2-resident).
// DOUBLE-BUFFERED K-loop (one barrier/iter): the global_load_lds for tile k+1
// is issued before the MFMA block of tile k, so the barrier's vmcnt(0) drain
// overlaps the MFMAs instead of serializing with them.
// Epilogue repacks C through LDS for coalesced full-line vector stores.
// Requires M%128==0, N%128==0, K%64==0, lda/ldb 8-elem, ldc 4-elem aligned.
// ---------------------------------------------------------------------------
#define TM 128
#define TN 128
#define TK 64

__device__ __forceinline__ void load16_lds(const bf16_t* g, bf16_t* l) {
  __builtin_amdgcn_global_load_lds(
      (__attribute__((address_space(1))) void*)const_cast<bf16_t*>(g),
      (__attribute__((address_space(3))) void*)l, 16, 0, 0);
}

template <typename CT>
__global__ __launch_bounds__(256, 2) void gemm_bt(
    const bf16_t* __restrict__ A, int lda, size_t strA,
    const bf16_t* __restrict__ B, int ldb, size_t strB,
    CT* __restrict__ C, int ldc, size_t strC,
    const float* __restrict__ bias, float scale,
    int M, int N, int K) {
  // 2 x 32 KB ping-pong buffers (64 KB total -> 2 blocks/CU, LDS-bound)
  __shared__ __align__(16) char smem[2][(TM * TK + TN * TK) * 2];

  A += (size_t)blockIdx.z * strA;
  B += (size_t)blockIdx.z * strB;
  C += (size_t)blockIdx.z * strC;
  int m0 = blockIdx.x * TM;   // M-tile on x (XCD swizzle)
  int n0 = blockIdx.y * TN;
  int tid  = threadIdx.x;
  int lane = tid & 63;
  int wv   = tid >> 6;        // wave id 0..3
  int wrow = wv >> 1;         // 2x2 waves of 64x64
  int wcol = wv & 1;

  f32x4 acc[4][4];
  #pragma unroll
  for (int i = 0; i < 4; i++)
    #pragma unroll
    for (int j = 0; j < 4; j++) acc[i][j] = (f32x4)0.f;

  int lrow = lane & 15;
  int lk   = (lane >> 4) * 8;

  // stage 128x64 bf16 A- and B-tiles into buffer `buf`: 4 wave-issues each,
  // 16B/lane, LDS layout [row][k] (128 B rows) in exact lane order.
  auto stage = [&](int k0, int buf) {
    bf16_t* As = (bf16_t*)smem[buf];
    bf16_t* Bs = As + TM * TK;
    #pragma unroll
    for (int i = 0; i < 4; i++) {
      int chunk  = i * 4096 + wv * 1024;   // wave-uniform byte offset in tile
      int lchunk = chunk + lane * 16;      // this lane's byte offset
      int row = lchunk >> 7;               // 128 B per row (TK*2)
      int kb  = (lchunk & 127) >> 1;       // element offset within row
      load16_lds(A + (size_t)(m0 + row) * lda + k0 + kb, As + (chunk >> 1));
      load16_lds(B + (size_t)(n0 + row) * ldb + k0 + kb, Bs + (chunk >> 1));
    }
  };

  int nk = K / TK;
  stage(0, 0);
  __syncthreads();             // tile 0 resident

  for (int kk = 0; kk < nk; kk++) {
    if (kk + 1 < nk) stage((kk + 1) * TK, (kk + 1) & 1);  // overlap w/ MFMAs

    const bf16_t* As = (const bf16_t*)smem[kk & 1];
    const bf16_t* Bs = As + TM * TK;
    #pragma unroll
    for (int ks = 0; ks < TK; ks += 32) {
      bf16x8 af[4], bfr[4];
      #pragma unroll
      for (int i = 0; i < 4; i++)
        af[i] = *(const bf16x8*)&As[(wrow * 64 + i * 16 + lrow) * TK + ks + lk];
      #pragma unroll
      for (int j = 0; j < 4; j++)
        bfr[j] = *(const bf16x8*)&Bs[(wcol * 64 + j * 16 + lrow) * TK + ks + lk];
      #pragma unroll
      for (int i = 0; i < 4; i++)
        #pragma unroll
        for (int j = 0; j < 4; j++)
          acc[i][j] = __builtin_amdgcn_mfma_f32_16x16x32_bf16(af[i], bfr[j],
                                                              acc[i][j], 0, 0, 0);
    }
    __syncthreads();  // (a) all reads of buf[kk&1] done before overwrite;
                      // (b) vmcnt(0) drain retires tile kk+1 staging
  }

  // ---- epilogue: repack C through LDS (two 64x128 fp32 halves = 32 KB) ----
  // acc mapping: col = lane&15 (+j*16, +wcol*64), row = (lane>>4)*4+r (+i*16,
  // +wrow*64)  [m89-verified]
  float* Cs = (float*)smem[0];
  #pragma unroll
  for (int h = 0; h < 2; h++) {
    __syncthreads();
    if (wrow == h) {           // wave-uniform branch
      #pragma unroll
      for (int i = 0; i < 4; i++) {
        int lr = i * 16 + (lane >> 4) * 4;            // row within 64-row half
        #pragma unroll
        for (int j = 0; j < 4; j++) {
          int lc = wcol * 64 + j * 16 + (lane & 15);  // col within 128
          #pragma unroll
          for (int r = 0; r < 4; r++)
            Cs[(lr + r) * 128 + lc] = acc[i][j][r];
        }
      }
    }
    __syncthreads();
    // linear readback: 8192 floats, 256 threads -> 8 float4 per thread
    #pragma unroll
    for (int io = 0; io < 8; io++) {
      int idx = io * 256 + tid;        // 0..2047 float4 groups
      int r   = idx >> 5;              // row 0..63
      int c4  = (idx & 31) * 4;        // col 0..124
      float4 v = *(const float4*)&Cs[r * 128 + c4];
      int grow = m0 + h * 64 + r;
      int gcol = n0 + c4;
      float4 bv = bias ? *(const float4*)&bias[gcol] : make_float4(0, 0, 0, 0);
      v.x = v.x * scale + bv.x; v.y = v.y * scale + bv.y;
      v.z = v.z * scale + bv.z; v.w = v.w * scale + bv.w;
      store4(C + (size_t)grow * ldc + gcol, v);
    }
  }
}

// ---------------------------------------------------------------------------
// Host-side launcher.  Peak workspace: 168 MiB (same as proven-good R2).
//   [W bf16 8MiB][SC 64MiB fp16 logits, first 32MiB doubles as bf16 IN copy]
//   [Qb 32][Kb 32 (becomes VT after scores)][Xb 32 (V, then attention X)]
// ---------------------------------------------------------------------------
extern "C" void kernel_launch(void* const* d_in, const int* in_sizes, int n_in,
                              void* d_out, int out_size, void* d_ws, size_t ws_size,
                              hipStream_t stream) {
  const float* query = (const float*)d_in[0];
  const float* key_  = (const float*)d_in[1];
  const float* value = (const float*)d_in[2];
  const float* Wq = (const float*)d_in[3];
  const float* bq = (const float*)d_in[4];
  const float* Wk = (const float*)d_in[5];
  const float* bk = (const float*)d_in[6];
  const float* Wv = (const float*)d_in[7];
  const float* bv = (const float*)d_in[8];
  const float* Wo = (const float*)d_in[9];
  const float* bo = (const float*)d_in[10];
  float* out = (float*)d_out;

  const int Bb = 8, S = 2048, D = 1024;
  const int MS = Bb * S;                    // 16384
  const size_t ND = (size_t)MS * D;         // 16.7M elements (32 MiB bf16)
  const size_t WD = (size_t)D * D;          // 1M elements (2 MiB bf16)

  char* ws = (char*)d_ws;
  bf16_t* Wqb = (bf16_t*)ws;                //  8 MiB of weights
  bf16_t* Wkb = Wqb + WD;
  bf16_t* Wvb = Wkb + WD;
  bf16_t* Wob = Wvb + WD;
  f16_t*  SC  = (f16_t*)(Wob + WD);         // 64 MiB: fp16 logits [8][S][S]
  bf16_t* IN  = (bf16_t*)SC;                //   overlay: bf16 input copies
  bf16_t* Qb  = (bf16_t*)((char*)SC + (size_t)Bb * S * S * 2);  // 32 MiB
  bf16_t* Kb  = Qb + ND;                    // 32 MiB; VT overlays after scores
  bf16_t* VT  = Kb;
  bf16_t* Xb  = Kb + ND;                    // 32 MiB: V bf16, then X
  // total: 168 MiB

  const int n4i = (int)(ND / 4), n4w = (int)(WD / 4);

  // weights
  cvt_f32_bf16<<<dim3(n4w / 256), 256, 0, stream>>>(Wq, Wqb, n4w);
  cvt_f32_bf16<<<dim3(n4w / 256), 256, 0, stream>>>(Wk, Wkb, n4w);
  cvt_f32_bf16<<<dim3(n4w / 256), 256, 0, stream>>>(Wv, Wvb, n4w);
  cvt_f32_bf16<<<dim3(n4w / 256), 256, 0, stream>>>(Wo, Wob, n4w);

  // projections, one input at a time through IN (M=16384, N=K=1024)
  dim3 pgrid(MS / TM, D / TN, 1);           // x = M-tiles (XCD swizzle)
  cvt_f32_bf16<<<dim3(n4i / 256), 256, 0, stream>>>(query, IN, n4i);
  gemm_bt<bf16_t><<<pgrid, 256, 0, stream>>>(
      IN, D, 0, Wqb, D, 0, Qb, D, 0, bq, 1.f, MS, D, D);
  cvt_f32_bf16<<<dim3(n4i / 256), 256, 0, stream>>>(key_, IN, n4i);
  gemm_bt<bf16_t><<<pgrid, 256, 0, stream>>>(
      IN, D, 0, Wkb, D, 0, Kb, D, 0, bk, 1.f, MS, D, D);
  cvt_f32_bf16<<<dim3(n4i / 256), 256, 0, stream>>>(value, IN, n4i);
  gemm_bt<bf16_t><<<pgrid, 256, 0, stream>>>(
      IN, D, 0, Wvb, D, 0, Xb, D, 0, bv, 1.f, MS, D, D);  // V into Xb (temp)

  // scores = Q @ K^T / sqrt(128) -> fp16, ALL batches (M=N=2048, K=1024).
  // (IN region is dead now; SC may overwrite it.)
  gemm_bt<f16_t><<<dim3(S / TM, S / TN, Bb), 256, 0, stream>>>(
      Qb, D, (size_t)S * D, Kb, D, (size_t)S * D, SC, S, (size_t)S * S,
      nullptr, 0.08838834764831845f, S, S, D);

  // V^T per batch: [2048,1024] -> [1024,2048] into VT (=Kb, dead after scores)
  transpose_bf16<<<dim3(D / 64, S / 64, Bb), 256, 0, stream>>>(Xb, VT, S, D);

  // softmax all rows -> bf16 P in place (row pitch 2048 elements)
  softmax_rows_f16<<<dim3(Bb * S), 256, 0, stream>>>(SC);

  // X = P @ (V^T)^T, ALL batches (M=2048, N=1024, K=2048), 1024 blocks
  gemm_bt<bf16_t><<<dim3(S / TM, D / TN, Bb), 256, 0, stream>>>(
      (const bf16_t*)SC, S, (size_t)S * S, VT, S, (size_t)D * S,
      Xb, D, (size_t)S * D, nullptr, 1.f, S, D, S);

  // out = X @ Wo^T + bo -> fp32 (M=16384, N=K=1024)
  gemm_bt<float><<<pgrid, 256, 0, stream>>>(
      Xb, D, 0, Wob, D, 0, out, D, 0, bo, 1.f, MS, D, D);
}